// Round 2
// baseline (224.648 us; speedup 1.0000x reference)
//
#include <hip/hip_runtime.h>

#define B_    16
#define N_    65536
#define C_    256
#define DIN_  16
#define DOUT_ 16

// workspace layout (floats):
//   s      [DIN_][B_][C_]    = 65536 floats  (s[i][b][k])
//   off    [B_][C_][DOUT_]   = 65536 floats  (includes /N and +b1)
//   wd_t   [C_][DIN_*DOUT_]  = 65536 floats  (wd_t[c][i*16+o])
//   c_of_n [N_]              = 65536 ints    (cluster id of source row n)

// ---------------------------------------------------------------------------
// K1: fused prep + cluster sums. (unchanged)
// ---------------------------------------------------------------------------
__global__ __launch_bounds__(256) void k_sum_prep(
    const float* __restrict__ x, const float* __restrict__ w_diag,
    const int* __restrict__ P, float* __restrict__ s,
    float* __restrict__ wd_t, int* __restrict__ c_of_n)
{
    int bid = blockIdx.x;
    int t = threadIdx.x;
    if (bid >= B_ * C_) {
        int r = bid - B_ * C_;
        if (r < 256) {
            int o = r >> 4, i = r & 15;
            wd_t[t * 256 + i * 16 + o] = w_diag[r * C_ + t];  // coalesced read
        } else {
            int k = r - 256;
            c_of_n[P[k * 256 + t]] = k;
        }
        return;
    }
    int b = bid >> 8;
    int k = bid & (C_ - 1);
    int q  = t & 3;
    int rg = t >> 2;
    float4 acc = make_float4(0.f, 0.f, 0.f, 0.f);
    const int jbase = k << 8;
    #pragma unroll
    for (int m = 0; m < 4; ++m) {
        int n = P[jbase + rg + 64 * m];
        const float4* row =
            reinterpret_cast<const float4*>(x + ((size_t)(b * N_ + n)) * DIN_);
        float4 v = row[q];
        acc.x += v.x; acc.y += v.y; acc.z += v.z; acc.w += v.w;
    }
    #pragma unroll
    for (int mask = 4; mask <= 32; mask <<= 1) {
        acc.x += __shfl_xor(acc.x, mask, 64);
        acc.y += __shfl_xor(acc.y, mask, 64);
        acc.z += __shfl_xor(acc.z, mask, 64);
        acc.w += __shfl_xor(acc.w, mask, 64);
    }
    __shared__ float4 part[4][4];
    int lane = t & 63, wave = t >> 6;
    if (lane < 4) part[wave][lane] = acc;
    __syncthreads();
    if (t < 16) {
        int qq = t >> 2, comp = t & 3;
        float v = 0.f;
        #pragma unroll
        for (int w = 0; w < 4; ++w) {
            const float* p = reinterpret_cast<const float*>(&part[w][qq]);
            v += p[comp];
        }
        int i = qq * 4 + comp;
        s[i * (B_ * C_) + b * C_ + k] = v;
    }
}

// ---------------------------------------------------------------------------
// K2 (rewritten again): off[b,c,o] = invN * sum_{i,k} w_off[o,i,c,k]*s[i,b,k] + b1[o]
// grid = C_ = 256 blocks (1/CU), 256 threads = 4 waves.
// wave wq owns o-quad {4wq..4wq+3}; lane kq owns k-quad. acc[4o][16b] in regs.
// Pipeline invariants:
//   - w for iter i is in regs BEFORE iter i starts (ping-pong wA/wB).
//   - s slice i+2 is ISSUED at top of iter i, written to LDS at end of iter i+1
//     (depth-2 cover; all global loads issue before the FMA block).
//   - FMAs read only LDS + regs: no vmcnt wait on the FMA path.
// Tail: fold-halving wave reduce (63 shfls), lane l holds value bitrev6(l).
// ---------------------------------------------------------------------------
__global__ __launch_bounds__(256) void k_off(
    const float* __restrict__ w_off, const float* __restrict__ s,
    const float* __restrict__ b1, float* __restrict__ off)
{
    const int c  = blockIdx.x;
    const int t  = threadIdx.x;
    const int kq = t & 63;
    const int wq = t >> 6;

    __shared__ float4 slds[2][1024];   // [buf][b*64 + kq], 16 KB per buf

    const float4* s4 = reinterpret_cast<const float4*>(s);
    const float4* w4 = reinterpret_cast<const float4*>(w_off);

    // float4 index of w_off[o][i=0][c][kq*4]: o*262144 + c*64 + kq  (< 2^23, int ok)
    int wbase[4];
    #pragma unroll
    for (int o4 = 0; o4 < 4; ++o4)
        wbase[o4] = (wq * 4 + o4) * 262144 + c * 64 + kq;

    float acc[64];   // acc[o4*16 + b]
    #pragma unroll
    for (int z = 0; z < 64; ++z) acc[z] = 0.f;

    float4 sA[4], sB[4], wA[4], wB[4], s0[4];

    // prologue: slice0 -> LDS buf0; slice1 -> sA regs; w(0) -> wA regs
    #pragma unroll
    for (int j = 0; j < 4; ++j) s0[j] = s4[t + 256 * j];
    #pragma unroll
    for (int o4 = 0; o4 < 4; ++o4) wA[o4] = w4[wbase[o4]];
    #pragma unroll
    for (int j = 0; j < 4; ++j) sA[j] = s4[1024 + t + 256 * j];
    #pragma unroll
    for (int j = 0; j < 4; ++j) slds[0][t + 256 * j] = s0[j];
    __syncthreads();

#define K2_BODY(I, WC, WN, SR, SI, RB, WBUF)                                   \
    {                                                                          \
        if ((I) + 2 < DIN_) {                                                  \
            _Pragma("unroll")                                                  \
            for (int j = 0; j < 4; ++j)                                        \
                SI[j] = s4[((I) + 2) * 1024 + t + 256 * j];                    \
        }                                                                      \
        if ((I) + 1 < DIN_) {                                                  \
            _Pragma("unroll")                                                  \
            for (int o4 = 0; o4 < 4; ++o4)                                     \
                WN[o4] = w4[wbase[o4] + ((I) + 1) * 16384];                    \
        }                                                                      \
        _Pragma("unroll")                                                      \
        for (int b = 0; b < 16; ++b) {                                         \
            float4 sv = slds[RB][b * 64 + kq];                                 \
            _Pragma("unroll")                                                  \
            for (int o4 = 0; o4 < 4; ++o4)                                     \
                acc[o4 * 16 + b] += WC[o4].x * sv.x + WC[o4].y * sv.y          \
                                  + WC[o4].z * sv.z + WC[o4].w * sv.w;         \
        }                                                                      \
        if ((I) + 1 < DIN_) {                                                  \
            _Pragma("unroll")                                                  \
            for (int j = 0; j < 4; ++j)                                        \
                slds[WBUF][t + 256 * j] = SR[j];                               \
            __syncthreads();                                                   \
        }                                                                      \
    }

    #pragma unroll 1
    for (int ih = 0; ih < DIN_ / 2; ++ih) {
        const int i0 = ih * 2;
        K2_BODY(i0,     wA, wB, sA, sB, 0, 1)
        K2_BODY(i0 + 1, wB, wA, sB, sA, 1, 0)
    }
#undef K2_BODY

    // fold-halving reduce: 64 values x 64 lanes -> 1 value/lane (63 shfls)
#define FOLD(MASK, CNT)                                                        \
    {                                                                          \
        const bool hi_ = (kq & (MASK)) != 0;                                   \
        _Pragma("unroll")                                                      \
        for (int j = 0; j < (CNT); ++j) {                                      \
            float keep = hi_ ? acc[j + (CNT)] : acc[j];                        \
            float send = hi_ ? acc[j] : acc[j + (CNT)];                        \
            acc[j] = keep + __shfl_xor(send, (MASK), 64);                      \
        }                                                                      \
    }
    FOLD(1, 32) FOLD(2, 16) FOLD(4, 8) FOLD(8, 4) FOLD(16, 2) FOLD(32, 1)
#undef FOLD

    // lane l holds the full sum for flat index j = bitrev6(l) = o4*16 + b
    int j = ((kq >> 5) & 1) | ((kq >> 3) & 2) | ((kq >> 1) & 4)
          | ((kq << 1) & 8) | ((kq << 3) & 16) | ((kq << 5) & 32);
    int b  = j & 15;
    int o4 = j >> 4;
    int o  = wq * 4 + o4;
    off[((b << 8) + c) * DOUT_ + o] = acc[0] * (1.0f / (float)N_) + b1[o];
}

// ---------------------------------------------------------------------------
// K3: sequential apply. (unchanged)
// ---------------------------------------------------------------------------
__global__ __launch_bounds__(256) void k_apply_seq(
    const float* __restrict__ x, const int* __restrict__ c_of_n,
    const float* __restrict__ wd_t, const float* __restrict__ off,
    float* __restrict__ out)
{
    int t = threadIdx.x;
    int lr = t >> 2, q = t & 3;
    int n = blockIdx.x * 64 + lr;
    int c = c_of_n[n];

    const float4* wd4 = reinterpret_cast<const float4*>(wd_t);
    float4 wds[16];
    #pragma unroll
    for (int i = 0; i < 16; ++i) wds[i] = wd4[c * 64 + i * 4 + q];

    const float4* x4   = reinterpret_cast<const float4*>(x);
    const float4* off4 = reinterpret_cast<const float4*>(off);
    float4* out4       = reinterpret_cast<float4*>(out);

    #pragma unroll 2
    for (int b = 0; b < B_; ++b) {
        size_t rowbase = ((size_t)(b * N_ + n)) * 4;
        float4 x0 = x4[rowbase + 0];
        float4 x1 = x4[rowbase + 1];
        float4 x2 = x4[rowbase + 2];
        float4 x3 = x4[rowbase + 3];
        float4 acc = off4[((size_t)((b << 8) + c)) * 4 + q];
        float xv[16];
        xv[0]=x0.x; xv[1]=x0.y; xv[2]=x0.z; xv[3]=x0.w;
        xv[4]=x1.x; xv[5]=x1.y; xv[6]=x1.z; xv[7]=x1.w;
        xv[8]=x2.x; xv[9]=x2.y; xv[10]=x2.z; xv[11]=x2.w;
        xv[12]=x3.x; xv[13]=x3.y; xv[14]=x3.z; xv[15]=x3.w;
        #pragma unroll
        for (int i = 0; i < 16; ++i) {
            acc.x += xv[i] * wds[i].x;
            acc.y += xv[i] * wds[i].y;
            acc.z += xv[i] * wds[i].z;
            acc.w += xv[i] * wds[i].w;
        }
        out4[rowbase + q] = acc;
    }
}

extern "C" void kernel_launch(void* const* d_in, const int* in_sizes, int n_in,
                              void* d_out, int out_size, void* d_ws, size_t ws_size,
                              hipStream_t stream) {
    const float* x      = (const float*)d_in[0];
    const float* w_diag = (const float*)d_in[1];
    const float* w_off  = (const float*)d_in[2];
    const float* b1     = (const float*)d_in[3];
    const int*   P      = (const int*)d_in[4];
    float* out    = (float*)d_out;
    float* s      = (float*)d_ws;          // 65536 floats
    float* off    = s + 65536;             // 65536 floats
    float* wd_t   = off + 65536;           // 65536 floats
    int*   c_of_n = (int*)(wd_t + 65536);  // 65536 ints

    k_sum_prep<<<B_ * C_ + 512, 256, 0, stream>>>(x, w_diag, P, s, wd_t, c_of_n);
    k_off<<<C_, 256, 0, stream>>>(w_off, s, b1, off);
    k_apply_seq<<<N_ / 64, 256, 0, stream>>>(x, c_of_n, wd_t, off, out);
}

// Round 3
// 208.306 us; speedup vs baseline: 1.0785x; 1.0785x over previous
//
#include <hip/hip_runtime.h>

#define B_    16
#define N_    65536
#define C_    256
#define DIN_  16
#define DOUT_ 16

// workspace layout (floats):
//   s      [DIN_][B_][C_]    = 65536 floats  (s[i][b][k])
//   off    [B_][C_][DOUT_]   = 65536 floats  (includes /N and +b1)
//   wd_t   [C_][DIN_*DOUT_]  = 65536 floats  (wd_t[c][i*16+o])
//   c_of_n [N_]              = 65536 ints    (cluster id of source row n)

// ---------------------------------------------------------------------------
// K1: fused prep + cluster sums. (unchanged)
// ---------------------------------------------------------------------------
__global__ __launch_bounds__(256) void k_sum_prep(
    const float* __restrict__ x, const float* __restrict__ w_diag,
    const int* __restrict__ P, float* __restrict__ s,
    float* __restrict__ wd_t, int* __restrict__ c_of_n)
{
    int bid = blockIdx.x;
    int t = threadIdx.x;
    if (bid >= B_ * C_) {
        int r = bid - B_ * C_;
        if (r < 256) {
            int o = r >> 4, i = r & 15;
            wd_t[t * 256 + i * 16 + o] = w_diag[r * C_ + t];  // coalesced read
        } else {
            int k = r - 256;
            c_of_n[P[k * 256 + t]] = k;
        }
        return;
    }
    int b = bid >> 8;
    int k = bid & (C_ - 1);
    int q  = t & 3;
    int rg = t >> 2;
    float4 acc = make_float4(0.f, 0.f, 0.f, 0.f);
    const int jbase = k << 8;
    #pragma unroll
    for (int m = 0; m < 4; ++m) {
        int n = P[jbase + rg + 64 * m];
        const float4* row =
            reinterpret_cast<const float4*>(x + ((size_t)(b * N_ + n)) * DIN_);
        float4 v = row[q];
        acc.x += v.x; acc.y += v.y; acc.z += v.z; acc.w += v.w;
    }
    #pragma unroll
    for (int mask = 4; mask <= 32; mask <<= 1) {
        acc.x += __shfl_xor(acc.x, mask, 64);
        acc.y += __shfl_xor(acc.y, mask, 64);
        acc.z += __shfl_xor(acc.z, mask, 64);
        acc.w += __shfl_xor(acc.w, mask, 64);
    }
    __shared__ float4 part[4][4];
    int lane = t & 63, wave = t >> 6;
    if (lane < 4) part[wave][lane] = acc;
    __syncthreads();
    if (t < 16) {
        int qq = t >> 2, comp = t & 3;
        float v = 0.f;
        #pragma unroll
        for (int w = 0; w < 4; ++w) {
            const float* p = reinterpret_cast<const float*>(&part[w][qq]);
            v += p[comp];
        }
        int i = qq * 4 + comp;
        s[i * (B_ * C_) + b * C_ + k] = v;
    }
}

// ---------------------------------------------------------------------------
// K2: off[b,c,o] = invN * sum_{i,k} w_off[o,i,c,k]*s[i,b,k] + b1[o]
// grid = 512 blocks (c = bid>>1, o-half og = bid&1), 512 threads = 8 waves.
//   wave w: oq = w&1 (o0 = og*8 + oq*4), bh = w>>1 (b0 = bh*4).
//   lane kq owns k-quad. acc[o4*4+bq] = 16 regs.
// Barrier discipline (the round-2 fix): RAW s_barrier + explicit lgkmcnt(0)
//   only — NO __syncthreads(), so the compiler emits counted per-use vmcnt
//   waits and the depth-2 s-prefetch + depth-1 w-prefetch stay in flight
//   across barriers. FMAs read only LDS + regs loaded >=1 iter earlier.
// ---------------------------------------------------------------------------
__global__ __launch_bounds__(512) void k_off(
    const float* __restrict__ w_off, const float* __restrict__ s,
    const float* __restrict__ b1, float* __restrict__ off)
{
    const int c  = (int)blockIdx.x >> 1;
    const int og = (int)blockIdx.x & 1;
    const int t  = threadIdx.x;       // 0..511
    const int kq = t & 63;
    const int w  = t >> 6;            // 0..7
    const int oq = w & 1;
    const int bh = w >> 1;            // b-quarter
    const int b0 = bh * 4;
    const int o0 = og * 8 + oq * 4;

    __shared__ float4 slds[2][1024];  // [buf][b*64 + kq], 16 KB per buf

    const float4* s4 = reinterpret_cast<const float4*>(s);
    const float4* w4 = reinterpret_cast<const float4*>(w_off);

    // float4 index of w_off[o][i][c][kq*4] = o*262144 + i*16384 + c*64 + kq
    int wbase[4];
    #pragma unroll
    for (int o4 = 0; o4 < 4; ++o4)
        wbase[o4] = (o0 + o4) * 262144 + c * 64 + kq;

    float acc[16];    // acc[o4*4 + bq]
    #pragma unroll
    for (int z = 0; z < 16; ++z) acc[z] = 0.f;

    float4 wA[4], wB[4], sA[2], sB[2];

    // prologue: slice0 -> LDS buf0; w(0) -> wA; slice1 -> sA
    {
        float4 p0 = s4[t], p1 = s4[t + 512];
        #pragma unroll
        for (int o4 = 0; o4 < 4; ++o4) wA[o4] = w4[wbase[o4]];
        sA[0] = s4[1024 + t];
        sA[1] = s4[1024 + t + 512];
        slds[0][t] = p0;
        slds[0][t + 512] = p1;
        asm volatile("s_waitcnt lgkmcnt(0)" ::: "memory");
        __builtin_amdgcn_s_barrier();
    }

#define K2_BODY(I, WC, WN, SR, SI, RB)                                         \
    {                                                                          \
        if ((I) + 2 < DIN_) {                                                  \
            SI[0] = s4[((I) + 2) * 1024 + t];                                  \
            SI[1] = s4[((I) + 2) * 1024 + t + 512];                            \
        }                                                                      \
        if ((I) + 1 < DIN_) {                                                  \
            _Pragma("unroll")                                                  \
            for (int o4 = 0; o4 < 4; ++o4)                                     \
                WN[o4] = w4[wbase[o4] + ((I) + 1) * 16384];                    \
        }                                                                      \
        _Pragma("unroll")                                                      \
        for (int bq = 0; bq < 4; ++bq) {                                       \
            float4 sv = slds[RB][(b0 + bq) * 64 + kq];                         \
            _Pragma("unroll")                                                  \
            for (int o4 = 0; o4 < 4; ++o4)                                     \
                acc[o4 * 4 + bq] += WC[o4].x * sv.x + WC[o4].y * sv.y          \
                                  + WC[o4].z * sv.z + WC[o4].w * sv.w;         \
        }                                                                      \
        if ((I) + 1 < DIN_) {                                                  \
            slds[(RB) ^ 1][t]       = SR[0];                                   \
            slds[(RB) ^ 1][t + 512] = SR[1];                                   \
            asm volatile("s_waitcnt lgkmcnt(0)" ::: "memory");                 \
            __builtin_amdgcn_s_barrier();                                      \
        }                                                                      \
    }

    #pragma unroll
    for (int ih = 0; ih < DIN_ / 2; ++ih) {
        K2_BODY(2 * ih,     wA, wB, sA, sB, 0)
        K2_BODY(2 * ih + 1, wB, wA, sB, sA, 1)
    }
#undef K2_BODY

    // fold-halving reduce: 16 values x 64 lanes (4 folds within 16-lane
    // groups, then 2 plain xor-adds across groups). Lane l<16 ends with the
    // full k-sum of value j = bitrev4(l).
#define FOLD(MASK, CNT)                                                        \
    {                                                                          \
        const bool hi_ = (kq & (MASK)) != 0;                                   \
        _Pragma("unroll")                                                      \
        for (int j = 0; j < (CNT); ++j) {                                      \
            float keep = hi_ ? acc[j + (CNT)] : acc[j];                        \
            float send = hi_ ? acc[j] : acc[j + (CNT)];                        \
            acc[j] = keep + __shfl_xor(send, (MASK), 64);                      \
        }                                                                      \
    }
    FOLD(1, 8) FOLD(2, 4) FOLD(4, 2) FOLD(8, 1)
#undef FOLD
    acc[0] += __shfl_xor(acc[0], 16, 64);
    acc[0] += __shfl_xor(acc[0], 32, 64);

    if (kq < 16) {
        int j  = ((kq & 1) << 3) | ((kq & 2) << 1) | ((kq & 4) >> 1) | ((kq & 8) >> 3);
        int b  = b0 + (j & 3);
        int o  = o0 + (j >> 2);
        off[((b << 8) + c) * DOUT_ + o] = acc[0] * (1.0f / (float)N_) + b1[o];
    }
}

// ---------------------------------------------------------------------------
// K3: sequential apply. (unchanged)
// ---------------------------------------------------------------------------
__global__ __launch_bounds__(256) void k_apply_seq(
    const float* __restrict__ x, const int* __restrict__ c_of_n,
    const float* __restrict__ wd_t, const float* __restrict__ off,
    float* __restrict__ out)
{
    int t = threadIdx.x;
    int lr = t >> 2, q = t & 3;
    int n = blockIdx.x * 64 + lr;
    int c = c_of_n[n];

    const float4* wd4 = reinterpret_cast<const float4*>(wd_t);
    float4 wds[16];
    #pragma unroll
    for (int i = 0; i < 16; ++i) wds[i] = wd4[c * 64 + i * 4 + q];

    const float4* x4   = reinterpret_cast<const float4*>(x);
    const float4* off4 = reinterpret_cast<const float4*>(off);
    float4* out4       = reinterpret_cast<float4*>(out);

    #pragma unroll 2
    for (int b = 0; b < B_; ++b) {
        size_t rowbase = ((size_t)(b * N_ + n)) * 4;
        float4 x0 = x4[rowbase + 0];
        float4 x1 = x4[rowbase + 1];
        float4 x2 = x4[rowbase + 2];
        float4 x3 = x4[rowbase + 3];
        float4 acc = off4[((size_t)((b << 8) + c)) * 4 + q];
        float xv[16];
        xv[0]=x0.x; xv[1]=x0.y; xv[2]=x0.z; xv[3]=x0.w;
        xv[4]=x1.x; xv[5]=x1.y; xv[6]=x1.z; xv[7]=x1.w;
        xv[8]=x2.x; xv[9]=x2.y; xv[10]=x2.z; xv[11]=x2.w;
        xv[12]=x3.x; xv[13]=x3.y; xv[14]=x3.z; xv[15]=x3.w;
        #pragma unroll
        for (int i = 0; i < 16; ++i) {
            acc.x += xv[i] * wds[i].x;
            acc.y += xv[i] * wds[i].y;
            acc.z += xv[i] * wds[i].z;
            acc.w += xv[i] * wds[i].w;
        }
        out4[rowbase + q] = acc;
    }
}

extern "C" void kernel_launch(void* const* d_in, const int* in_sizes, int n_in,
                              void* d_out, int out_size, void* d_ws, size_t ws_size,
                              hipStream_t stream) {
    const float* x      = (const float*)d_in[0];
    const float* w_diag = (const float*)d_in[1];
    const float* w_off  = (const float*)d_in[2];
    const float* b1     = (const float*)d_in[3];
    const int*   P      = (const int*)d_in[4];
    float* out    = (float*)d_out;
    float* s      = (float*)d_ws;          // 65536 floats
    float* off    = s + 65536;             // 65536 floats
    float* wd_t   = off + 65536;           // 65536 floats
    int*   c_of_n = (int*)(wd_t + 65536);  // 65536 ints

    k_sum_prep<<<B_ * C_ + 512, 256, 0, stream>>>(x, w_diag, P, s, wd_t, c_of_n);
    k_off<<<C_ * 2, 512, 0, stream>>>(w_off, s, b1, off);
    k_apply_seq<<<N_ / 64, 256, 0, stream>>>(x, c_of_n, wd_t, off, out);
}